// Round 1
// baseline (1976.593 us; speedup 1.0000x reference)
//
#include <hip/hip_runtime.h>

#define T_STEPS 2000
#define BATCH   256
#define F_IN    80
#define HDIM    64

template<int N> struct IC { static constexpr int v = N; };

typedef _Float16 h2 __attribute__((ext_vector_type(2)));
typedef _Float16 h4 __attribute__((ext_vector_type(4)));
typedef _Float16 h8 __attribute__((ext_vector_type(8)));

union U8 { h8 v; h2 p[4]; };
union U4 { h4 v; h2 p[2]; };

// ---- fast transcendentals (fp32; logits threshold 1.77e-2) ----
__device__ __forceinline__ float sigm_f(float v) {
    float e = __expf(-v);
    return __builtin_amdgcn_rcpf(1.f + e);
}
__device__ __forceinline__ float tanh_f(float v) {
    v = fminf(fmaxf(v, -15.f), 15.f);
    float e = __expf(-2.f * v);
    return (1.f - e) * __builtin_amdgcn_rcpf(1.f + e);
}
// quad butterfly sum (lanes ks=0..3) via DPP quad_perm — VALU only.
__device__ __forceinline__ float qred(float v) {
    v += __int_as_float(__builtin_amdgcn_mov_dpp(__float_as_int(v), 0xB1, 0xF, 0xF, true));
    v += __int_as_float(__builtin_amdgcn_mov_dpp(__float_as_int(v), 0x4E, 0xF, 0xF, true));
    return v;
}
// LDS-only barrier: waits own LDS ops but leaves global loads in flight
// (keeps gx prefetch / x prefetch outstanding across the step boundary).
__device__ __forceinline__ void barrier_lds() {
    __builtin_amdgcn_s_waitcnt(0xC07F);   // vmcnt=63, expcnt=7, lgkmcnt=0
    __builtin_amdgcn_s_barrier();
}
// v_dot2_f32_f16: 2 fp16 MACs, fp32 accumulate, one VALU instr.
__device__ __forceinline__ float fdot2(h2 a, h2 b, float c) {
    return __builtin_amdgcn_fdot2(a, b, c, false);
}
__device__ __forceinline__ h2 mk2(float a, float b) {
    h2 r; r.x = (_Float16)a; r.y = (_Float16)b; return r;
}

// ---------------------------------------------------------------------------
// Prep: Wih0 fp32 -> fp16 copy; bias_ext[c] = bih0[c] (+ bhh0[c] for r,z gates)
// ---------------------------------------------------------------------------
__global__ void prep_kernel(const float* __restrict__ Wih0,
                            const float* __restrict__ bih0,
                            const float* __restrict__ bhh0,
                            _Float16* __restrict__ Wh2,
                            float* __restrict__ bias_ext)
{
    int i = blockIdx.x * blockDim.x + threadIdx.x;
    if (i < 192 * F_IN) Wh2[i] = (_Float16)Wih0[i];
    if (i < 192)        bias_ext[i] = bih0[i] + (i < 128 ? bhh0[i] : 0.f);
}

// ---------------------------------------------------------------------------
// gx GEMM: gx[b,t,c] = bias_ext[c] + sum_f x[b,t,f]*Wih0[c,f], stored fp16.
// One block per (b,t) row; 192 threads = one output column each.
// fp16 inputs / fp32 accumulate — identical numerics to the in-loop version.
// ---------------------------------------------------------------------------
__global__ __launch_bounds__(192)
void gx_gemm(const float* __restrict__ x,        // [B,T,80] fp32
             const _Float16* __restrict__ Wh2,   // [192,80] fp16
             const float* __restrict__ bias_ext, // [192]
             _Float16* __restrict__ gxp)         // [B*T,192] fp16
{
    const int r = blockIdx.x;
    const int c = threadIdx.x;
    __shared__ __align__(16) _Float16 xs[F_IN];
    const float* xr = x + (size_t)r * F_IN;
    if (c < 40) {
        float2 v = ((const float2*)xr)[c];
        *(h2*)(&xs[2 * c]) = mk2(v.x, v.y);
    }
    __syncthreads();
    const h8* wp = (const h8*)(Wh2 + c * F_IN);
    const h8* xp = (const h8*)xs;
    float acc = bias_ext[c];
    #pragma unroll
    for (int q = 0; q < 10; ++q) {
        U8 wq, xq;
        wq.v = wp[q];
        xq.v = xp[q];      // LDS broadcast (same addr all lanes) — conflict-free
        #pragma unroll
        for (int p = 0; p < 4; ++p) acc = fdot2(wq.p[p], xq.p[p], acc);
    }
    gxp[(size_t)r * 192 + c] = (_Float16)acc;
}

// ---------------------------------------------------------------------------
// Fused 2-layer GRU scan. One block per batch row. 512 threads = 8 waves.
//   waves 0..3 : layer 0. lane owns unit jw = 16*(w&3)+(lane>>2); K-chunk ks=lane&3.
//   waves 4..7 : layer 1, one step behind.
// USE_GX==1: L0's input projection gx comes precomputed (fp16, bias-folded);
//            per step L0 just loads 3 halves (distance-2 register prefetch).
//            wave 7 has no staging duty.
// USE_GX==0: original self-contained path (fallback when workspace too small).
// ---------------------------------------------------------------------------
template<int USE_GX>
__global__ __launch_bounds__(512, 2)
void gru_fused(const float* __restrict__ x,      // [B,T,F]
               const _Float16* __restrict__ gx,  // [B*T,192] fp16 (USE_GX only)
               const float* __restrict__ hin,    // [2,B,H]
               const float* __restrict__ Wih0,   // [192,80]
               const float* __restrict__ Whh0,   // [192,64]
               const float* __restrict__ bih0, const float* __restrict__ bhh0,
               const float* __restrict__ Wih1,   // [192,64]
               const float* __restrict__ Whh1,   // [192,64]
               const float* __restrict__ bih1, const float* __restrict__ bhh1,
               float* __restrict__ out_hidden)   // [2,B,H] region of d_out
{
    const int b    = blockIdx.x;
    const int tid  = threadIdx.x;
    const int lane = tid & 63;
    const int w    = tid >> 6;                  // 0..7
    const bool isL1 = (w >= 4);
    const int ks   = lane & 3;
    const int gg   = lane >> 2;
    const int jw   = ((w & 3) << 4) + gg;       // unit this lane owns

    // fp16 LDS. x chunks padded to 24 halves; h flat 64 halves (chunk = 16 halves).
    __shared__ __align__(16) _Float16 xsh[2][96];
    __shared__ __align__(16) _Float16 h0s[2][64];
    __shared__ __align__(16) _Float16 h1s[2][64];

    // ---- weights -> fp16 register pairs ----
    h2 wxr[10], wxz[10], wxn[10];   // L0(!USE_GX): 20 x-elems; L1: 16 h0-elems
    h2 whr[8],  whz[8],  whn[8];    // L0: Whh0 chunk; L1: Whh1 chunk
    float bihr = 0.f, bihz = 0.f, bihn = 0.f, bhhr = 0.f, bhhz = 0.f, bhhn = 0.f;
    if (!isL1) {
        const int c2 = ks * 16;
        const float* s0 = Whh0 + jw * HDIM + c2;
        const float* s1 = Whh0 + (64 + jw) * HDIM + c2;
        const float* s2 = Whh0 + (128 + jw) * HDIM + c2;
        #pragma unroll
        for (int k = 0; k < 8; ++k) {
            whr[k] = mk2(s0[2*k], s0[2*k+1]);
            whz[k] = mk2(s1[2*k], s1[2*k+1]);
            whn[k] = mk2(s2[2*k], s2[2*k+1]);
        }
        bhhn = bhh0[128 + jw];
        if constexpr (USE_GX == 0) {
            const int c = ks * 20;
            const float* r0 = Wih0 + jw * F_IN + c;
            const float* r1 = Wih0 + (64 + jw) * F_IN + c;
            const float* r2 = Wih0 + (128 + jw) * F_IN + c;
            #pragma unroll
            for (int k = 0; k < 10; ++k) {
                wxr[k] = mk2(r0[2*k], r0[2*k+1]);
                wxz[k] = mk2(r1[2*k], r1[2*k+1]);
                wxn[k] = mk2(r2[2*k], r2[2*k+1]);
            }
            bihr = bih0[jw];       bhhr = bhh0[jw];
            bihz = bih0[64 + jw];  bhhz = bhh0[64 + jw];
            bihn = bih0[128 + jw];
        }
    } else {
        const int c2 = ks * 16;
        const float* r0 = Wih1 + jw * HDIM + c2;
        const float* r1 = Wih1 + (64 + jw) * HDIM + c2;
        const float* r2 = Wih1 + (128 + jw) * HDIM + c2;
        const float* s0 = Whh1 + jw * HDIM + c2;
        const float* s1 = Whh1 + (64 + jw) * HDIM + c2;
        const float* s2 = Whh1 + (128 + jw) * HDIM + c2;
        #pragma unroll
        for (int k = 0; k < 8; ++k) {
            wxr[k] = mk2(r0[2*k], r0[2*k+1]);
            wxz[k] = mk2(r1[2*k], r1[2*k+1]);
            wxn[k] = mk2(r2[2*k], r2[2*k+1]);
            whr[k] = mk2(s0[2*k], s0[2*k+1]);
            whz[k] = mk2(s1[2*k], s1[2*k+1]);
            whn[k] = mk2(s2[2*k], s2[2*k+1]);
        }
        wxr[8] = mk2(0.f, 0.f); wxr[9] = mk2(0.f, 0.f);
        wxz[8] = mk2(0.f, 0.f); wxz[9] = mk2(0.f, 0.f);
        wxn[8] = mk2(0.f, 0.f); wxn[9] = mk2(0.f, 0.f);
        bihr = bih1[jw] + bhh1[jw];              // r: merged bias
        bihz = bih1[64 + jw] + bhh1[64 + jw];    // z: merged bias
        bihn = bih1[128 + jw];                   // n: x-side bias
        bhhn = bhh1[128 + jw];                   // n: h-side bias
    }

    // ---- state init ----
    float hreg = isL1 ? hin[BATCH * HDIM + b * HDIM + jw]
                      : hin[b * HDIM + jw];
    if (w == 0) {                                // slot 1 = parity of "step -1"
        h0s[1][lane] = (_Float16)hin[b * HDIM + lane];
        h1s[1][lane] = (_Float16)hin[BATCH * HDIM + b * HDIM + lane];
    }
    const float* xrow = x + (size_t)b * T_STEPS * F_IN;
    const int xe = 2 * lane;                     // element pair this lane stages
    const int xc = xe / 20, xpp = xe % 20;       // chunk / pos
    float2 xa = make_float2(0.f, 0.f), xb = make_float2(0.f, 0.f);
    if constexpr (USE_GX == 0) {
        if (w == 7 && lane < 40) {               // stage x0,x1; prefetch x2,x3
            float2 v0 = ((const float2*)(xrow + 0 * F_IN))[lane];
            float2 v1 = ((const float2*)(xrow + 1 * F_IN))[lane];
            *(h2*)(&xsh[0][xc * 24 + xpp]) = mk2(v0.x, v0.y);
            *(h2*)(&xsh[1][xc * 24 + xpp]) = mk2(v1.x, v1.y);
            xa = ((const float2*)(xrow + 2 * F_IN))[lane];
            xb = ((const float2*)(xrow + 3 * F_IN))[lane];
        }
    }

    // ---- gx register prefetch (USE_GX): slot0 = even steps, slot1 = odd ----
    _Float16 pr0 = (_Float16)0.f, pz0 = (_Float16)0.f, pn0 = (_Float16)0.f;
    _Float16 pr1 = (_Float16)0.f, pz1 = (_Float16)0.f, pn1 = (_Float16)0.f;
    const _Float16* gp0 = nullptr;
    const _Float16* gp1 = nullptr;
    if constexpr (USE_GX) {
        if (!isL1) {
            const _Float16* gb = gx + (size_t)b * T_STEPS * 192 + jw;
            pr0 = gb[0];       pz0 = gb[64];        pn0 = gb[128];       // step 0
            pr1 = gb[192];     pz1 = gb[256];       pn1 = gb[320];       // step 1
            gp0 = gb + 2 * 192;                      // next even-step load (i=2)
            gp1 = gb + 3 * 192;                      // next odd-step load  (i=3)
        }
    }

    __syncthreads();   // prologue only

    // gx[0] from x slot 0 (fallback path only)
    float gxr = 0.f, gxz = 0.f, gxn = 0.f;
    if constexpr (USE_GX == 0) {
        if (!isL1) {
            U8 x0, x1; U4 x2;
            x0.v = ((const h8*)(&xsh[0][ks * 24]))[0];
            x1.v = ((const h8*)(&xsh[0][ks * 24]))[1];
            x2.v = *(const h4*)(&xsh[0][ks * 24 + 16]);
            float ar = 0.f, az = 0.f, an = 0.f;
            #pragma unroll
            for (int q = 0; q < 4; ++q) {
                ar = fdot2(wxr[q], x0.p[q], ar);
                az = fdot2(wxz[q], x0.p[q], az);
                an = fdot2(wxn[q], x0.p[q], an);
            }
            #pragma unroll
            for (int q = 0; q < 4; ++q) {
                ar = fdot2(wxr[4 + q], x1.p[q], ar);
                az = fdot2(wxz[4 + q], x1.p[q], az);
                an = fdot2(wxn[4 + q], x1.p[q], an);
            }
            #pragma unroll
            for (int q = 0; q < 2; ++q) {
                ar = fdot2(wxr[8 + q], x2.p[q], ar);
                az = fdot2(wxz[8 + q], x2.p[q], az);
                an = fdot2(wxn[8 + q], x2.p[q], an);
            }
            gxr = qred(ar) + bihr; gxz = qred(az) + bihz; gxn = qred(an) + bihn;
        }
    }

    auto step = [&](int i, auto ipc) {
        constexpr int IP = decltype(ipc)::v;   // i&1
        constexpr int IO = IP ^ 1;             // (i-1)&1 == (i+1)&1

        // ---- x staging (fallback only, wave 7) ----
        if constexpr (USE_GX == 0) {
            if (w == 7 && lane < 40) {
                float2 v = (IP == 0) ? xa : xb;
                *(h2*)(&xsh[IP][xc * 24 + xpp]) = mk2(v.x, v.y);
                if (i <= T_STEPS - 5) {
                    float2 nv = ((const float2*)(xrow + (size_t)(i + 4) * F_IN))[lane];
                    if (IP == 0) xa = nv; else xb = nv;
                }
            }
        }

        if (!isL1) {
            // batched fp16 reads: h0[i-1] (2 b128)
            U8 ha, hb;
            ha.v = ((const h8*)(&h0s[IO][ks * 16]))[0];
            hb.v = ((const h8*)(&h0s[IO][ks * 16]))[1];
            U8 x0, x1; U4 x2;
            if constexpr (USE_GX == 0) {
                x0.v = ((const h8*)(&xsh[IO][ks * 24]))[0];
                x1.v = ((const h8*)(&xsh[IO][ks * 24]))[1];
                x2.v = *(const h4*)(&xsh[IO][ks * 24 + 16]);
            }

            // gx consume (loaded 2 steps ago) + prefetch step i+2 into slot IP
            float gr_f = 0.f, gz_f = 0.f, gn_f = 0.f;
            if constexpr (USE_GX) {
                if (IP == 0) { gr_f = (float)pr0; gz_f = (float)pz0; gn_f = (float)pn0; }
                else         { gr_f = (float)pr1; gz_f = (float)pz1; gn_f = (float)pn1; }
                if (IP == 0) { pr0 = gp0[0]; pz0 = gp0[64]; pn0 = gp0[128]; gp0 += 2 * 192; }
                else         { pr1 = gp1[0]; pz1 = gp1[64]; pn1 = gp1[128]; gp1 += 2 * 192; }
            }

            // on-chain: gh = Whh0 . h0[i-1]
            float ahr = 0.f, ahz = 0.f, ahn = 0.f;
            #pragma unroll
            for (int q = 0; q < 4; ++q) {
                ahr = fdot2(whr[q], ha.p[q], ahr);
                ahz = fdot2(whz[q], ha.p[q], ahz);
                ahn = fdot2(whn[q], ha.p[q], ahn);
            }
            #pragma unroll
            for (int q = 0; q < 4; ++q) {
                ahr = fdot2(whr[4 + q], hb.p[q], ahr);
                ahz = fdot2(whz[4 + q], hb.p[q], ahz);
                ahn = fdot2(whn[4 + q], hb.p[q], ahn);
            }
            // gates + update for step i
            float r, z, n;
            if constexpr (USE_GX) {
                r = sigm_f(gr_f + qred(ahr));                 // bih+bhh folded in gx
                z = sigm_f(gz_f + qred(ahz));
                n = tanh_f(gn_f + r * (qred(ahn) + bhhn));    // bihn folded in gx
            } else {
                r = sigm_f(gxr + qred(ahr) + bhhr);
                z = sigm_f(gxz + qred(ahz) + bhhz);
                n = tanh_f(gxn + r * (qred(ahn) + bhhn));
            }
            hreg = (1.f - z) * n + z * hreg;
            if (ks == 0) h0s[IP][jw] = (_Float16)hreg;

            // off-chain: gx[i+1] = Wih0 . x[i+1] (fallback only)
            if constexpr (USE_GX == 0) {
                float axr = 0.f, axz = 0.f, axn = 0.f;
                #pragma unroll
                for (int q = 0; q < 4; ++q) {
                    axr = fdot2(wxr[q], x0.p[q], axr);
                    axz = fdot2(wxz[q], x0.p[q], axz);
                    axn = fdot2(wxn[q], x0.p[q], axn);
                }
                #pragma unroll
                for (int q = 0; q < 4; ++q) {
                    axr = fdot2(wxr[4 + q], x1.p[q], axr);
                    axz = fdot2(wxz[4 + q], x1.p[q], axz);
                    axn = fdot2(wxn[4 + q], x1.p[q], axn);
                }
                #pragma unroll
                for (int q = 0; q < 2; ++q) {
                    axr = fdot2(wxr[8 + q], x2.p[q], axr);
                    axz = fdot2(wxz[8 + q], x2.p[q], axz);
                    axn = fdot2(wxn[8 + q], x2.p[q], axn);
                }
                gxr = qred(axr) + bihr;
                gxz = qred(axz) + bihz;
                gxn = qred(axn) + bihn;
            }
        } else if (i >= 1) {
            // L1 step t=i-1: inputs h0[i-1] (slot IO), h1[i-2] (slot IP)
            U8 aa, ab, ba, bb;
            aa.v = ((const h8*)(&h0s[IO][ks * 16]))[0];
            ab.v = ((const h8*)(&h0s[IO][ks * 16]))[1];
            ba.v = ((const h8*)(&h1s[IP][ks * 16]))[0];
            bb.v = ((const h8*)(&h1s[IP][ks * 16]))[1];
            float ar = 0.f, az = 0.f, anx = 0.f, anh = 0.f;
            #pragma unroll
            for (int q = 0; q < 4; ++q) {
                ar  = fdot2(wxr[q], aa.p[q], ar);
                az  = fdot2(wxz[q], aa.p[q], az);
                anx = fdot2(wxn[q], aa.p[q], anx);
            }
            #pragma unroll
            for (int q = 0; q < 4; ++q) {
                ar  = fdot2(wxr[4 + q], ab.p[q], ar);
                az  = fdot2(wxz[4 + q], ab.p[q], az);
                anx = fdot2(wxn[4 + q], ab.p[q], anx);
            }
            #pragma unroll
            for (int q = 0; q < 4; ++q) {
                ar  = fdot2(whr[q], ba.p[q], ar);
                az  = fdot2(whz[q], ba.p[q], az);
                anh = fdot2(whn[q], ba.p[q], anh);
            }
            #pragma unroll
            for (int q = 0; q < 4; ++q) {
                ar  = fdot2(whr[4 + q], bb.p[q], ar);
                az  = fdot2(whz[4 + q], bb.p[q], az);
                anh = fdot2(whn[4 + q], bb.p[q], anh);
            }
            float r = sigm_f(qred(ar) + bihr);
            float z = sigm_f(qred(az) + bihz);
            float n = tanh_f(qred(anx) + bihn + r * (qred(anh) + bhhn));
            hreg = (1.f - z) * n + z * hreg;
            if (ks == 0) h1s[IO][jw] = (_Float16)hreg;
        }

        barrier_lds();
    };

    for (int ii = 0; ii < T_STEPS / 2; ++ii) {
        step(2 * ii,     IC<0>{});
        step(2 * ii + 1, IC<1>{});
    }

    // ---- epilogue i = T_STEPS (even, IP=0, IO=1): L1 processes step T-1 ----
    if (isL1) {
        U8 aa, ab, ba, bb;
        aa.v = ((const h8*)(&h0s[1][ks * 16]))[0];   // h0[T-1]
        ab.v = ((const h8*)(&h0s[1][ks * 16]))[1];
        ba.v = ((const h8*)(&h1s[0][ks * 16]))[0];   // h1[T-2]
        bb.v = ((const h8*)(&h1s[0][ks * 16]))[1];
        float ar = 0.f, az = 0.f, anx = 0.f, anh = 0.f;
        #pragma unroll
        for (int q = 0; q < 4; ++q) {
            ar  = fdot2(wxr[q], aa.p[q], ar);
            az  = fdot2(wxz[q], aa.p[q], az);
            anx = fdot2(wxn[q], aa.p[q], anx);
        }
        #pragma unroll
        for (int q = 0; q < 4; ++q) {
            ar  = fdot2(wxr[4 + q], ab.p[q], ar);
            az  = fdot2(wxz[4 + q], ab.p[q], az);
            anx = fdot2(wxn[4 + q], ab.p[q], anx);
        }
        #pragma unroll
        for (int q = 0; q < 4; ++q) {
            ar  = fdot2(whr[q], ba.p[q], ar);
            az  = fdot2(whz[q], ba.p[q], az);
            anh = fdot2(whn[q], ba.p[q], anh);
        }
        #pragma unroll
        for (int q = 0; q < 4; ++q) {
            ar  = fdot2(whr[4 + q], bb.p[q], ar);
            az  = fdot2(whz[4 + q], bb.p[q], az);
            anh = fdot2(whn[4 + q], bb.p[q], anh);
        }
        float r = sigm_f(qred(ar) + bihr);
        float z = sigm_f(qred(az) + bihz);
        float n = tanh_f(qred(anx) + bihn + r * (qred(anh) + bhhn));
        hreg = (1.f - z) * n + z * hreg;
    }

    // ---- final states (lane's own fp32 hreg) ----
    if (ks == 0) {
        if (!isL1) out_hidden[b * HDIM + jw] = hreg;                 // h0[T-1]
        else       out_hidden[BATCH * HDIM + b * HDIM + jw] = hreg;  // h1[T-1]
    }
}

// logits[b][o] = b_fc[o] + sum_j relu(h1T[b][j]) * W_fc[o][j]
__global__ void fc_kernel(const float* __restrict__ hidden,   // [2,B,H] region
                          const float* __restrict__ Wfc,      // [29,64]
                          const float* __restrict__ bfc,      // [29]
                          float* __restrict__ logits)         // [B,29]
{
    const int b = blockIdx.x;
    const int o = threadIdx.x;
    if (o < 29) {
        const float* hb = hidden + BATCH * HDIM + b * HDIM;   // h1T
        float acc = bfc[o];
        #pragma unroll
        for (int j = 0; j < HDIM; ++j)
            acc += fmaxf(hb[j], 0.f) * Wfc[o * HDIM + j];
        logits[b * 29 + o] = acc;
    }
}

extern "C" void kernel_launch(void* const* d_in, const int* in_sizes, int n_in,
                              void* d_out, int out_size, void* d_ws, size_t ws_size,
                              hipStream_t stream) {
    const float* x    = (const float*)d_in[0];
    const float* h    = (const float*)d_in[1];
    const float* Wih0 = (const float*)d_in[2];
    const float* Whh0 = (const float*)d_in[3];
    const float* bih0 = (const float*)d_in[4];
    const float* bhh0 = (const float*)d_in[5];
    const float* Wih1 = (const float*)d_in[6];
    const float* Whh1 = (const float*)d_in[7];
    const float* bih1 = (const float*)d_in[8];
    const float* bhh1 = (const float*)d_in[9];
    const float* Wfc  = (const float*)d_in[10];
    const float* bfc  = (const float*)d_in[11];

    float* out    = (float*)d_out;
    float* logits = out;                      // [256,29]
    float* hidden = out + BATCH * 29;         // [2,256,64]

    // Workspace layout: [gx fp16 (B*T*192 + pad)][Wih0 fp16][bias_ext f32]
    const size_t gx_elems = (size_t)BATCH * T_STEPS * 192 + 1024;  // pad: guardless prefetch
    const size_t gx_bytes = gx_elems * sizeof(_Float16);           // 16B-aligned size
    const size_t w_bytes  = (size_t)192 * F_IN * sizeof(_Float16);
    const size_t need     = gx_bytes + w_bytes + 192 * sizeof(float);

    if (d_ws != nullptr && ws_size >= need) {
        _Float16* gxp      = (_Float16*)d_ws;
        _Float16* Wh2      = (_Float16*)((char*)d_ws + gx_bytes);
        float*    bias_ext = (float*)((char*)d_ws + gx_bytes + w_bytes);

        prep_kernel<<<60, 256, 0, stream>>>(Wih0, bih0, bhh0, Wh2, bias_ext);
        gx_gemm<<<BATCH * T_STEPS, 192, 0, stream>>>(x, Wh2, bias_ext, gxp);
        gru_fused<1><<<BATCH, 512, 0, stream>>>(
            x, gxp, h, Wih0, Whh0, bih0, bhh0, Wih1, Whh1, bih1, bhh1, hidden);
    } else {
        gru_fused<0><<<BATCH, 512, 0, stream>>>(
            x, nullptr, h, Wih0, Whh0, bih0, bhh0, Wih1, Whh1, bih1, bhh1, hidden);
    }

    fc_kernel<<<BATCH, 64, 0, stream>>>(hidden, Wfc, bfc, logits);
}

// Round 3
// 1481.851 us; speedup vs baseline: 1.3339x; 1.3339x over previous
//
#include <hip/hip_runtime.h>

#define T_STEPS 2000
#define BATCH   256
#define F_IN    80
#define HDIM    64

template<int N> struct IC { static constexpr int v = N; };

typedef _Float16 h2 __attribute__((ext_vector_type(2)));
typedef _Float16 h8 __attribute__((ext_vector_type(8)));

union U8 { h8 v; h2 p[4]; };

// ---- fast transcendentals (fp32; logits threshold 1.77e-2) ----
__device__ __forceinline__ float sigm_f(float v) {
    float e = __expf(-v);
    return __builtin_amdgcn_rcpf(1.f + e);
}
__device__ __forceinline__ float tanh_f(float v) {
    v = fminf(fmaxf(v, -15.f), 15.f);
    float e = __expf(-2.f * v);
    return (1.f - e) * __builtin_amdgcn_rcpf(1.f + e);
}
// LDS-only barrier: waits own LDS ops but leaves global loads in flight.
__device__ __forceinline__ void barrier_lds() {
    __builtin_amdgcn_s_waitcnt(0xC07F);   // vmcnt=63, expcnt=7, lgkmcnt=0
    __builtin_amdgcn_s_barrier();
}
// v_dot2_f32_f16: 2 fp16 MACs, fp32 accumulate, one VALU instr.
__device__ __forceinline__ float fdot2(h2 a, h2 b, float c) {
    return __builtin_amdgcn_fdot2(a, b, c, false);
}
__device__ __forceinline__ h2 mk2(float a, float b) {
    h2 r; r.x = (_Float16)a; r.y = (_Float16)b; return r;
}

// ---------------------------------------------------------------------------
// gx GEMM: gx[r, c] = bias(c) + Wih0[c,:] . x[r,:]  for r in [0, B*T), c in [0,192)
// stored fp16, biases folded (bih0 all gates; +bhh0 for r,z gates).
// 2048 blocks x 1 wave; each wave owns 250 rows and columns {j, 64+j, 128+j}.
// Weights live in 120 VGPRs for the whole block; x rows stream through a
// ping-pong LDS buffer (intra-wave sync only — no barriers, no relaunches).
// ---------------------------------------------------------------------------
__global__ __launch_bounds__(64, 2)
void gx_gemm(const float* __restrict__ x,        // [B*T, 80] fp32
             const float* __restrict__ Wih0,     // [192, 80] fp32
             const float* __restrict__ bih0,
             const float* __restrict__ bhh0,
             _Float16* __restrict__ gxp)         // [B*T, 192] fp16
{
    const int j = threadIdx.x;                   // 0..63
    const long total = (long)BATCH * T_STEPS;
    const long per   = total / gridDim.x;        // 250
    const long r0    = (long)blockIdx.x * per;
    const long r1    = r0 + per;

    // weights: rows j, 64+j, 128+j of Wih0 -> fp16 pairs in registers
    h2 wr[40], wz[40], wn[40];
    {
        const float* a = Wih0 + (size_t)j * F_IN;
        const float* bb = Wih0 + (size_t)(64 + j) * F_IN;
        const float* c = Wih0 + (size_t)(128 + j) * F_IN;
        #pragma unroll
        for (int k = 0; k < 40; ++k) {
            wr[k] = mk2(a[2*k],  a[2*k+1]);
            wz[k] = mk2(bb[2*k], bb[2*k+1]);
            wn[k] = mk2(c[2*k],  c[2*k+1]);
        }
    }
    const float br = bih0[j]       + bhh0[j];
    const float bz = bih0[64 + j]  + bhh0[64 + j];
    const float bn = bih0[128 + j];

    __shared__ __align__(16) _Float16 xs[2][80];

    // stage row r0 into xs[0]
    if (j < 40) {
        float2 v = ((const float2*)(x + r0 * F_IN))[j];
        *(h2*)&xs[0][2 * j] = mk2(v.x, v.y);
    }
    for (long r = r0; r < r1; ++r) {
        const int cur = (int)(r - r0) & 1;
        // prefetch next row's x (global, hidden under compute)
        float2 v = make_float2(0.f, 0.f);
        const bool pf = (j < 40) && (r + 1 < r1);
        if (pf) v = ((const float2*)(x + (r + 1) * F_IN))[j];

        U8 xv[10];
        #pragma unroll
        for (int q = 0; q < 10; ++q) xv[q].v = ((const h8*)xs[cur])[q];

        float ar = br, az = bz, an = bn;
        #pragma unroll
        for (int q = 0; q < 10; ++q)
            #pragma unroll
            for (int p = 0; p < 4; ++p) {
                ar = fdot2(wr[4*q+p], xv[q].p[p], ar);
                az = fdot2(wz[4*q+p], xv[q].p[p], az);
                an = fdot2(wn[4*q+p], xv[q].p[p], an);
            }
        _Float16* g = gxp + r * 192;
        g[j]       = (_Float16)ar;
        g[64 + j]  = (_Float16)az;
        g[128 + j] = (_Float16)an;

        if (pf) *(h2*)&xs[cur ^ 1][2 * j] = mk2(v.x, v.y);
    }
}

// ---------------------------------------------------------------------------
// Fused 2-layer GRU scan. One block per batch row. 128 threads = 2 waves.
//   wave 0 = layer 0 (full-K per lane: lane j owns unit j, 96 fdot2/step)
//   wave 1 = layer 1, one step behind (192 fdot2/step)
// h0 handoff: 4-slot LDS ring + one 2-wave barrier per step.
// h1 recurrence: intra-wave LDS ping-pong (no barrier needed).
// All h broadcast reads are wave-uniform-address ds_read_b128 (conflict-free).
// ---------------------------------------------------------------------------
__global__ __launch_bounds__(128, 1)
void gru_scan(const _Float16* __restrict__ gx,   // [B*T, 192] fp16 (bias-folded)
              const float* __restrict__ hin,     // [2,B,H]
              const float* __restrict__ Whh0,    // [192,64]
              const float* __restrict__ bhh0,
              const float* __restrict__ Wih1,    // [192,64]
              const float* __restrict__ Whh1,    // [192,64]
              const float* __restrict__ bih1, const float* __restrict__ bhh1,
              float* __restrict__ out_hidden)    // [2,B,H] region of d_out
{
    const int b = blockIdx.x;
    const int j = threadIdx.x & 63;
    const int w = threadIdx.x >> 6;

    __shared__ __align__(16) _Float16 h0r[4][64];   // ring: slot i&3 = h0[i]
    __shared__ __align__(16) _Float16 h1r[2][64];   // ping-pong: slot i&1 = h1[i-1]

    if (w == 0) {
        // ---- layer 0 ----
        h2 whr[32], whz[32], whn[32];
        {
            const float* a0 = Whh0 + (size_t)j * HDIM;
            const float* a1 = Whh0 + (size_t)(64 + j) * HDIM;
            const float* a2 = Whh0 + (size_t)(128 + j) * HDIM;
            #pragma unroll
            for (int k = 0; k < 32; ++k) {
                whr[k] = mk2(a0[2*k], a0[2*k+1]);
                whz[k] = mk2(a1[2*k], a1[2*k+1]);
                whn[k] = mk2(a2[2*k], a2[2*k+1]);
            }
        }
        const float bn0h = bhh0[128 + j];
        float hreg = hin[b * HDIM + j];
        h0r[3][j] = (_Float16)hreg;               // slot (0-1)&3 = h0[-1]

        const _Float16* gbase = gx + (size_t)b * T_STEPS * 192;
        _Float16 grf[2], gzf[2], gnf[2];          // depth-2 gx prefetch
        grf[0] = gbase[j];        gzf[0] = gbase[64 + j];        gnf[0] = gbase[128 + j];
        grf[1] = gbase[192 + j];  gzf[1] = gbase[192 + 64 + j];  gnf[1] = gbase[192 + 128 + j];

        __syncthreads();

        auto stepL0 = [&](int i, auto c3) {
            constexpr int I3 = decltype(c3)::v;   // i&3
            constexpr int IP = I3 & 1;            // i&1
            constexpr int IR = (I3 + 3) & 3;      // (i-1)&3
            U8 hv[8];
            #pragma unroll
            for (int q = 0; q < 8; ++q) hv[q].v = ((const h8*)h0r[IR])[q];
            float ar  = (float)grf[IP];
            float az  = (float)gzf[IP];
            float gxn = (float)gnf[IP];
            float anh = bn0h;
            // prefetch gx[i+2]; clamp keeps the tail reads in-bounds (wave-uniform SALU)
            const int ipf = (i + 2 < T_STEPS) ? (i + 2) : (T_STEPS - 1);
            const _Float16* gnx = gbase + (size_t)ipf * 192 + j;
            grf[IP] = gnx[0]; gzf[IP] = gnx[64]; gnf[IP] = gnx[128];
            #pragma unroll
            for (int q = 0; q < 8; ++q)
                #pragma unroll
                for (int p = 0; p < 4; ++p) {
                    ar  = fdot2(whr[4*q+p], hv[q].p[p], ar);
                    az  = fdot2(whz[4*q+p], hv[q].p[p], az);
                    anh = fdot2(whn[4*q+p], hv[q].p[p], anh);
                }
            float r = sigm_f(ar);
            float z = sigm_f(az);
            float n = tanh_f(gxn + r * anh);
            hreg = (1.f - z) * n + z * hreg;
            h0r[I3][j] = (_Float16)hreg;
            barrier_lds();
        };

        for (int ii = 0; ii < T_STEPS / 4; ++ii) {
            const int i = 4 * ii;
            stepL0(i + 0, IC<0>{});
            stepL0(i + 1, IC<1>{});
            stepL0(i + 2, IC<2>{});
            stepL0(i + 3, IC<3>{});
        }
        out_hidden[b * HDIM + j] = hreg;          // h0[T-1]
    } else {
        // ---- layer 1 ----
        h2 xr1[32], xz1[32], xn1[32], hr1[32], hz1[32], hn1[32];
        {
            const float* p0 = Wih1 + (size_t)j * HDIM;
            const float* p1 = Wih1 + (size_t)(64 + j) * HDIM;
            const float* p2 = Wih1 + (size_t)(128 + j) * HDIM;
            const float* q0 = Whh1 + (size_t)j * HDIM;
            const float* q1 = Whh1 + (size_t)(64 + j) * HDIM;
            const float* q2 = Whh1 + (size_t)(128 + j) * HDIM;
            #pragma unroll
            for (int k = 0; k < 32; ++k) {
                xr1[k] = mk2(p0[2*k], p0[2*k+1]);
                xz1[k] = mk2(p1[2*k], p1[2*k+1]);
                xn1[k] = mk2(p2[2*k], p2[2*k+1]);
                hr1[k] = mk2(q0[2*k], q0[2*k+1]);
                hz1[k] = mk2(q1[2*k], q1[2*k+1]);
                hn1[k] = mk2(q2[2*k], q2[2*k+1]);
            }
        }
        const float br1  = bih1[j] + bhh1[j];             // r: merged bias
        const float bz1  = bih1[64 + j] + bhh1[64 + j];   // z: merged bias
        const float bn1x = bih1[128 + j];                 // n: x-side bias
        const float bn1h = bhh1[128 + j];                 // n: h-side bias
        float hreg = hin[BATCH * HDIM + b * HDIM + j];
        h1r[0][j] = (_Float16)hreg;                       // h1[-1]

        __syncthreads();

        auto stepL1 = [&](auto c3) {      // iteration i processes t = i-1
            constexpr int I3 = decltype(c3)::v;   // i&3
            constexpr int IP = I3 & 1;            // i&1
            constexpr int IR = (I3 + 3) & 3;      // (i-1)&3
            U8 hv[8], uv[8];
            #pragma unroll
            for (int q = 0; q < 8; ++q) hv[q].v = ((const h8*)h0r[IR])[q];     // h0[i-1]
            #pragma unroll
            for (int q = 0; q < 8; ++q) uv[q].v = ((const h8*)h1r[IP ^ 1])[q]; // h1[i-2]
            float ar = br1, az = bz1, anx = bn1x, anh = bn1h;
            #pragma unroll
            for (int q = 0; q < 8; ++q)
                #pragma unroll
                for (int p = 0; p < 4; ++p) {
                    ar  = fdot2(xr1[4*q+p], hv[q].p[p], ar);
                    az  = fdot2(xz1[4*q+p], hv[q].p[p], az);
                    anx = fdot2(xn1[4*q+p], hv[q].p[p], anx);
                }
            #pragma unroll
            for (int q = 0; q < 8; ++q)
                #pragma unroll
                for (int p = 0; p < 4; ++p) {
                    ar  = fdot2(hr1[4*q+p], uv[q].p[p], ar);
                    az  = fdot2(hz1[4*q+p], uv[q].p[p], az);
                    anh = fdot2(hn1[4*q+p], uv[q].p[p], anh);
                }
            float r = sigm_f(ar);
            float z = sigm_f(az);
            float n = tanh_f(anx + r * anh);
            hreg = (1.f - z) * n + z * hreg;
            h1r[IP][j] = (_Float16)hreg;
            barrier_lds();
        };

        // i = 0: L1 idle, barrier only
        barrier_lds();
        stepL1(IC<1>{});   // i = 1
        stepL1(IC<2>{});   // i = 2
        stepL1(IC<3>{});   // i = 3
        for (int ii = 1; ii < T_STEPS / 4; ++ii) {
            stepL1(IC<0>{});
            stepL1(IC<1>{});
            stepL1(IC<2>{});
            stepL1(IC<3>{});
        }
        // epilogue i = T_STEPS (=2000, I3=0): process t = T-1; no write/barrier
        {
            U8 hv[8], uv[8];
            #pragma unroll
            for (int q = 0; q < 8; ++q) hv[q].v = ((const h8*)h0r[3])[q];  // h0[1999]
            #pragma unroll
            for (int q = 0; q < 8; ++q) uv[q].v = ((const h8*)h1r[1])[q];  // h1[1998]
            float ar = br1, az = bz1, anx = bn1x, anh = bn1h;
            #pragma unroll
            for (int q = 0; q < 8; ++q)
                #pragma unroll
                for (int p = 0; p < 4; ++p) {
                    ar  = fdot2(xr1[4*q+p], hv[q].p[p], ar);
                    az  = fdot2(xz1[4*q+p], hv[q].p[p], az);
                    anx = fdot2(xn1[4*q+p], hv[q].p[p], anx);
                }
            #pragma unroll
            for (int q = 0; q < 8; ++q)
                #pragma unroll
                for (int p = 0; p < 4; ++p) {
                    ar  = fdot2(hr1[4*q+p], uv[q].p[p], ar);
                    az  = fdot2(hz1[4*q+p], uv[q].p[p], az);
                    anh = fdot2(hn1[4*q+p], uv[q].p[p], anh);
                }
            float r = sigm_f(ar);
            float z = sigm_f(az);
            float n = tanh_f(anx + r * anh);
            hreg = (1.f - z) * n + z * hreg;
        }
        out_hidden[BATCH * HDIM + b * HDIM + j] = hreg;   // h1[T-1]
    }
}

// logits[b][o] = b_fc[o] + sum_j relu(h1T[b][j]) * W_fc[o][j]
__global__ void fc_kernel(const float* __restrict__ hidden,   // [2,B,H] region
                          const float* __restrict__ Wfc,      // [29,64]
                          const float* __restrict__ bfc,      // [29]
                          float* __restrict__ logits)         // [B,29]
{
    const int b = blockIdx.x;
    const int o = threadIdx.x;
    if (o < 29) {
        const float* hb = hidden + BATCH * HDIM + b * HDIM;   // h1T
        float acc = bfc[o];
        #pragma unroll
        for (int j = 0; j < HDIM; ++j)
            acc += fmaxf(hb[j], 0.f) * Wfc[o * HDIM + j];
        logits[b * 29 + o] = acc;
    }
}

extern "C" void kernel_launch(void* const* d_in, const int* in_sizes, int n_in,
                              void* d_out, int out_size, void* d_ws, size_t ws_size,
                              hipStream_t stream) {
    const float* x    = (const float*)d_in[0];
    const float* h    = (const float*)d_in[1];
    const float* Wih0 = (const float*)d_in[2];
    const float* Whh0 = (const float*)d_in[3];
    const float* bih0 = (const float*)d_in[4];
    const float* bhh0 = (const float*)d_in[5];
    const float* Wih1 = (const float*)d_in[6];
    const float* Whh1 = (const float*)d_in[7];
    const float* bih1 = (const float*)d_in[8];
    const float* bhh1 = (const float*)d_in[9];
    const float* Wfc  = (const float*)d_in[10];
    const float* bfc  = (const float*)d_in[11];

    float* out    = (float*)d_out;
    float* logits = out;                      // [256,29]
    float* hidden = out + BATCH * 29;         // [2,256,64]

    // Workspace: gx fp16 [B*T][192] = 196,608,000 B. All accesses in-bounds
    // (scan-side prefetch row is clamped to T_STEPS-1).
    _Float16* gxp = (_Float16*)d_ws;

    gx_gemm<<<2048, 64, 0, stream>>>(x, Wih0, bih0, bhh0, gxp);
    gru_scan<<<BATCH, 128, 0, stream>>>(
        gxp, h, Whh0, bhh0, Wih1, Whh1, bih1, bhh1, hidden);
    fc_kernel<<<BATCH, 64, 0, stream>>>(hidden, Wfc, bfc, logits);
}

// Round 4
// 1121.718 us; speedup vs baseline: 1.7621x; 1.3211x over previous
//
#include <hip/hip_runtime.h>

#define T_STEPS 2000
#define BATCH   256
#define F_IN    80
#define HDIM    64

template<int N> struct IC { static constexpr int v = N; };

typedef _Float16 h2 __attribute__((ext_vector_type(2)));
typedef _Float16 h8 __attribute__((ext_vector_type(8)));

union U8 { h8 v; h2 p[4]; };

// ---- fast transcendentals (fp32; logits threshold 1.77e-2) ----
__device__ __forceinline__ float sigm_f(float v) {
    float e = __expf(-v);
    return __builtin_amdgcn_rcpf(1.f + e);
}
__device__ __forceinline__ float tanh_f(float v) {
    v = fminf(fmaxf(v, -15.f), 15.f);
    float e = __expf(-2.f * v);
    return (1.f - e) * __builtin_amdgcn_rcpf(1.f + e);
}
// LDS-only barrier: waits own LDS ops but leaves global loads in flight.
__device__ __forceinline__ void barrier_lds() {
    __builtin_amdgcn_s_waitcnt(0xC07F);   // vmcnt=63, expcnt=7, lgkmcnt=0
    __builtin_amdgcn_s_barrier();
}
// v_dot2_f32_f16: 2 fp16 MACs, fp32 accumulate, one VALU instr.
__device__ __forceinline__ float fdot2(h2 a, h2 b, float c) {
    return __builtin_amdgcn_fdot2(a, b, c, false);
}
__device__ __forceinline__ h2 mk2(float a, float b) {
    h2 r; r.x = (_Float16)a; r.y = (_Float16)b; return r;
}

// ---------------------------------------------------------------------------
// gx GEMM: gx[r,c] = bias(c) + Wih0[c,:] . x[r,:], fp16 out, biases folded.
// 2048 blocks x 1 wave x 250 rows. Weights in 120 VGPRs (float4 loads: 60
// vector loads, not 240 divergent scalars). x rows stream through a ping-pong
// LDS buffer with distance-2 register prefetch (intra-wave ordering only).
// ---------------------------------------------------------------------------
__global__ __launch_bounds__(64, 2)
void gx_gemm(const float* __restrict__ x,        // [B*T, 80] fp32
             const float* __restrict__ Wih0,     // [192, 80] fp32
             const float* __restrict__ bih0,
             const float* __restrict__ bhh0,
             _Float16* __restrict__ gxp)         // [B*T, 192] fp16
{
    const int j = threadIdx.x;                   // 0..63
    const long total = (long)BATCH * T_STEPS;
    const long per   = total / gridDim.x;        // 250
    const long r0    = (long)blockIdx.x * per;
    const long r1    = r0 + per;

    h2 wr[40], wz[40], wn[40];
    {
        const float4* a4 = (const float4*)(Wih0 + (size_t)j * F_IN);
        const float4* b4 = (const float4*)(Wih0 + (size_t)(64 + j) * F_IN);
        const float4* c4 = (const float4*)(Wih0 + (size_t)(128 + j) * F_IN);
        #pragma unroll
        for (int k = 0; k < 20; ++k) {
            float4 va = a4[k], vb = b4[k], vc = c4[k];
            wr[2*k] = mk2(va.x, va.y); wr[2*k+1] = mk2(va.z, va.w);
            wz[2*k] = mk2(vb.x, vb.y); wz[2*k+1] = mk2(vb.z, vb.w);
            wn[2*k] = mk2(vc.x, vc.y); wn[2*k+1] = mk2(vc.z, vc.w);
        }
    }
    const float br = bih0[j]       + bhh0[j];
    const float bz = bih0[64 + j]  + bhh0[64 + j];
    const float bn = bih0[128 + j];

    __shared__ __align__(16) _Float16 xs[2][80];

    if (j < 40) {
        float2 v = ((const float2*)(x + r0 * F_IN))[j];
        *(h2*)&xs[0][2 * j] = mk2(v.x, v.y);
    }
    float2 vn = make_float2(0.f, 0.f);
    if (j < 40 && r0 + 1 < r1) vn = ((const float2*)(x + (r0 + 1) * F_IN))[j];

    for (long r = r0; r < r1; ++r) {
        const int cur = (int)(r - r0) & 1;
        // issue distance-2 prefetch first (in flight across this row's compute)
        float2 v2 = make_float2(0.f, 0.f);
        if (j < 40 && r + 2 < r1) v2 = ((const float2*)(x + (r + 2) * F_IN))[j];

        U8 xv[10];
        #pragma unroll
        for (int q = 0; q < 10; ++q) xv[q].v = ((const h8*)xs[cur])[q];

        float ar = br, az = bz, an = bn;
        #pragma unroll
        for (int q = 0; q < 10; ++q)
            #pragma unroll
            for (int p = 0; p < 4; ++p) {
                ar = fdot2(wr[4*q+p], xv[q].p[p], ar);
                az = fdot2(wz[4*q+p], xv[q].p[p], az);
                an = fdot2(wn[4*q+p], xv[q].p[p], an);
            }
        _Float16* g = gxp + r * 192;
        g[j]       = (_Float16)ar;
        g[64 + j]  = (_Float16)az;
        g[128 + j] = (_Float16)an;

        // stage row r+1 (loaded one iteration ago; vmcnt long satisfied)
        if (j < 40 && r + 1 < r1) *(h2*)&xs[cur ^ 1][2 * j] = mk2(vn.x, vn.y);
        vn = v2;
    }
}

// ---------------------------------------------------------------------------
// Fused 2-layer GRU scan. One block per batch row. 192 threads = 3 waves,
// each wave holds exactly 96 weight VGPRs (allocator-proven budget):
//   w0: L0 recurrence   h0[i]   = GRU(gx[i], Whh0 . h0[i-1])
//   w1: L1 x-side       px[i-1] = bias + Wih1 . h0[i-1]      (no gates)
//   w2: L1 h-side+gates h1[i-2] = GRU(px[i-2], Whh1 . h1[i-3])
// One barrier per step. w0/w2 pre-read their own just-written h row BEFORE
// the barrier (intra-wave DS ordering) so ds_read latency hides in the
// barrier wait. w2 adds the cross-wave px partials AFTER its 96 fdot2,
// hiding that LDS latency under the dot block.
// ---------------------------------------------------------------------------
__global__ __launch_bounds__(192, 1)
void gru_scan(const _Float16* __restrict__ gx,   // [B*T, 192] fp16 (bias-folded)
              const float* __restrict__ hin,     // [2,B,H]
              const float* __restrict__ Whh0,    // [192,64]
              const float* __restrict__ bhh0,
              const float* __restrict__ Wih1,    // [192,64]
              const float* __restrict__ Whh1,    // [192,64]
              const float* __restrict__ bih1, const float* __restrict__ bhh1,
              float* __restrict__ out_hidden)    // [2,B,H] region of d_out
{
    const int b = blockIdx.x;
    const int j = threadIdx.x & 63;
    const int w = threadIdx.x >> 6;

    __shared__ __align__(16) _Float16 h0r[4][64];   // ring: slot i&3 = h0[i]
    __shared__ __align__(16) _Float16 h1r[2][64];   // ping-pong: slot t&1 = h1[t]
    __shared__ __align__(16) float    pxs[2][3][64];// ping-pong: slot t&1 = px[t]

    if (w == 0) {
        // ---- wave 0: layer-0 recurrence ----
        h2 whr[32], whz[32], whn[32];
        {
            const float4* a4 = (const float4*)(Whh0 + (size_t)j * HDIM);
            const float4* b4 = (const float4*)(Whh0 + (size_t)(64 + j) * HDIM);
            const float4* c4 = (const float4*)(Whh0 + (size_t)(128 + j) * HDIM);
            #pragma unroll
            for (int k = 0; k < 16; ++k) {
                float4 va = a4[k], vb = b4[k], vc = c4[k];
                whr[2*k]=mk2(va.x,va.y); whr[2*k+1]=mk2(va.z,va.w);
                whz[2*k]=mk2(vb.x,vb.y); whz[2*k+1]=mk2(vb.z,vb.w);
                whn[2*k]=mk2(vc.x,vc.y); whn[2*k+1]=mk2(vc.z,vc.w);
            }
        }
        const float bn0h = bhh0[128 + j];
        float hreg = hin[b * HDIM + j];
        h0r[3][j] = (_Float16)hreg;                 // h0[-1]
        U8 hv[8];
        #pragma unroll
        for (int q = 0; q < 8; ++q) hv[q].v = ((const h8*)h0r[3])[q];

        const _Float16* gbase = gx + (size_t)b * T_STEPS * 192;
        _Float16 grf[2], gzf[2], gnf[2];            // depth-2 gx prefetch
        grf[0] = gbase[j];       gzf[0] = gbase[64 + j];       gnf[0] = gbase[128 + j];
        grf[1] = gbase[192 + j]; gzf[1] = gbase[192 + 64 + j]; gnf[1] = gbase[192 + 128 + j];

        __syncthreads();

        auto stepL0 = [&](int i, auto c3) {
            constexpr int I3 = decltype(c3)::v;     // i&3
            constexpr int IP = I3 & 1;
            float ar  = (float)grf[IP];
            float az  = (float)gzf[IP];
            float gxn = (float)gnf[IP];
            float anh = bn0h;
            const int ipf = (i + 2 < T_STEPS) ? (i + 2) : (T_STEPS - 1);  // clamp: in-bounds
            const _Float16* gnx = gbase + (size_t)ipf * 192 + j;
            grf[IP] = gnx[0]; gzf[IP] = gnx[64]; gnf[IP] = gnx[128];
            #pragma unroll
            for (int q = 0; q < 8; ++q)
                #pragma unroll
                for (int p = 0; p < 4; ++p) {
                    ar  = fdot2(whr[4*q+p], hv[q].p[p], ar);
                    az  = fdot2(whz[4*q+p], hv[q].p[p], az);
                    anh = fdot2(whn[4*q+p], hv[q].p[p], anh);
                }
            float r = sigm_f(ar);
            float z = sigm_f(az);
            float n = tanh_f(gxn + r * anh);
            hreg = (1.f - z) * n + z * hreg;
            h0r[I3][j] = (_Float16)hreg;
            // pre-read own just-written row (intra-wave DS order); latency
            // completes during the barrier wait.
            #pragma unroll
            for (int q = 0; q < 8; ++q) hv[q].v = ((const h8*)h0r[I3])[q];
            barrier_lds();
        };

        stepL0(0, IC<0>{}); stepL0(1, IC<1>{}); stepL0(2, IC<2>{}); stepL0(3, IC<3>{});
        for (int ii = 1; ii < T_STEPS / 4; ++ii) {
            const int i = 4 * ii;
            stepL0(i + 0, IC<0>{}); stepL0(i + 1, IC<1>{});
            stepL0(i + 2, IC<2>{}); stepL0(i + 3, IC<3>{});
        }
        barrier_lds();                              // epilogue A (match w1/w2)
        out_hidden[b * HDIM + j] = hreg;            // h0[T-1]
    } else if (w == 1) {
        // ---- wave 1: layer-1 x-side projections ----
        h2 xr1[32], xz1[32], xn1[32];
        {
            const float4* a4 = (const float4*)(Wih1 + (size_t)j * HDIM);
            const float4* b4 = (const float4*)(Wih1 + (size_t)(64 + j) * HDIM);
            const float4* c4 = (const float4*)(Wih1 + (size_t)(128 + j) * HDIM);
            #pragma unroll
            for (int k = 0; k < 16; ++k) {
                float4 va = a4[k], vb = b4[k], vc = c4[k];
                xr1[2*k]=mk2(va.x,va.y); xr1[2*k+1]=mk2(va.z,va.w);
                xz1[2*k]=mk2(vb.x,vb.y); xz1[2*k+1]=mk2(vb.z,vb.w);
                xn1[2*k]=mk2(vc.x,vc.y); xn1[2*k+1]=mk2(vc.z,vc.w);
            }
        }
        const float brm = bih1[j] + bhh1[j];          // r: merged bias
        const float bzm = bih1[64 + j] + bhh1[64 + j];// z: merged bias
        const float bnx = bih1[128 + j];              // n: x-side bias

        __syncthreads();

        auto stepW1 = [&](auto c3) {   // at step i: px[i-1] = bias + Wih1.h0[i-1]
            constexpr int I3 = decltype(c3)::v;       // i&3
            constexpr int IR = (I3 + 3) & 3;          // (i-1)&3
            constexpr int PS = (I3 + 1) & 1;          // (i-1)&1
            U8 hv[8];
            #pragma unroll
            for (int q = 0; q < 8; ++q) hv[q].v = ((const h8*)h0r[IR])[q];
            float ar = brm, az = bzm, an = bnx;
            #pragma unroll
            for (int q = 0; q < 8; ++q)
                #pragma unroll
                for (int p = 0; p < 4; ++p) {
                    ar = fdot2(xr1[4*q+p], hv[q].p[p], ar);
                    az = fdot2(xz1[4*q+p], hv[q].p[p], az);
                    an = fdot2(xn1[4*q+p], hv[q].p[p], an);
                }
            pxs[PS][0][j] = ar;
            pxs[PS][1][j] = az;
            pxs[PS][2][j] = an;
            barrier_lds();
        };

        barrier_lds();                                // i = 0 (idle)
        stepW1(IC<1>{}); stepW1(IC<2>{}); stepW1(IC<3>{});
        for (int ii = 1; ii < T_STEPS / 4; ++ii) {
            stepW1(IC<0>{}); stepW1(IC<1>{});
            stepW1(IC<2>{}); stepW1(IC<3>{});
        }
        stepW1(IC<0>{});                              // epilogue A: px[T-1]
    } else {
        // ---- wave 2: layer-1 h-side + gates ----
        h2 hr1[32], hz1[32], hn1[32];
        {
            const float4* a4 = (const float4*)(Whh1 + (size_t)j * HDIM);
            const float4* b4 = (const float4*)(Whh1 + (size_t)(64 + j) * HDIM);
            const float4* c4 = (const float4*)(Whh1 + (size_t)(128 + j) * HDIM);
            #pragma unroll
            for (int k = 0; k < 16; ++k) {
                float4 va = a4[k], vb = b4[k], vc = c4[k];
                hr1[2*k]=mk2(va.x,va.y); hr1[2*k+1]=mk2(va.z,va.w);
                hz1[2*k]=mk2(vb.x,vb.y); hz1[2*k+1]=mk2(vb.z,vb.w);
                hn1[2*k]=mk2(vc.x,vc.y); hn1[2*k+1]=mk2(vc.z,vc.w);
            }
        }
        const float bnh = bhh1[128 + j];
        float hreg = hin[BATCH * HDIM + b * HDIM + j];
        h1r[1][j] = (_Float16)hreg;                   // h1[-1] at slot (-1)&1
        U8 uv[8];
        #pragma unroll
        for (int q = 0; q < 8; ++q) uv[q].v = ((const h8*)h1r[1])[q];

        __syncthreads();

        auto stepW2 = [&](auto c3) {   // at step i: t = i-2
            constexpr int I3 = decltype(c3)::v;       // i&3
            constexpr int IP = I3 & 1;                // t&1 == i&1
            // issue px reads first; consumed after the dot block (latency hidden)
            const float pr = pxs[IP][0][j];
            const float pz = pxs[IP][1][j];
            const float pn = pxs[IP][2][j];
            float ahr = 0.f, ahz = 0.f, anh = bnh;
            #pragma unroll
            for (int q = 0; q < 8; ++q)
                #pragma unroll
                for (int p = 0; p < 4; ++p) {
                    ahr = fdot2(hr1[4*q+p], uv[q].p[p], ahr);
                    ahz = fdot2(hz1[4*q+p], uv[q].p[p], ahz);
                    anh = fdot2(hn1[4*q+p], uv[q].p[p], anh);
                }
            float r = sigm_f(pr + ahr);
            float z = sigm_f(pz + ahz);
            float n = tanh_f(pn + r * anh);
            hreg = (1.f - z) * n + z * hreg;
            h1r[IP][j] = (_Float16)hreg;
            #pragma unroll
            for (int q = 0; q < 8; ++q) uv[q].v = ((const h8*)h1r[IP])[q];
            barrier_lds();
        };

        barrier_lds(); barrier_lds();                 // i = 0, 1 (idle)
        stepW2(IC<2>{}); stepW2(IC<3>{});
        for (int ii = 1; ii < T_STEPS / 4; ++ii) {
            stepW2(IC<0>{}); stepW2(IC<1>{});
            stepW2(IC<2>{}); stepW2(IC<3>{});
        }
        stepW2(IC<0>{});                              // epilogue A: t = T-2
        {   // tail: t = T-1 (no barrier; px[T-1] in pxs[1], uv = h1[T-2])
            const float pr = pxs[1][0][j];
            const float pz = pxs[1][1][j];
            const float pn = pxs[1][2][j];
            float ahr = 0.f, ahz = 0.f, anh = bnh;
            #pragma unroll
            for (int q = 0; q < 8; ++q)
                #pragma unroll
                for (int p = 0; p < 4; ++p) {
                    ahr = fdot2(hr1[4*q+p], uv[q].p[p], ahr);
                    ahz = fdot2(hz1[4*q+p], uv[q].p[p], ahz);
                    anh = fdot2(hn1[4*q+p], uv[q].p[p], anh);
                }
            float r = sigm_f(pr + ahr);
            float z = sigm_f(pz + ahz);
            float n = tanh_f(pn + r * anh);
            hreg = (1.f - z) * n + z * hreg;
        }
        out_hidden[BATCH * HDIM + b * HDIM + j] = hreg;   // h1[T-1]
    }
}

// logits[b][o] = b_fc[o] + sum_j relu(h1T[b][j]) * W_fc[o][j]
__global__ void fc_kernel(const float* __restrict__ hidden,   // [2,B,H] region
                          const float* __restrict__ Wfc,      // [29,64]
                          const float* __restrict__ bfc,      // [29]
                          float* __restrict__ logits)         // [B,29]
{
    const int b = blockIdx.x;
    const int o = threadIdx.x;
    if (o < 29) {
        const float* hb = hidden + BATCH * HDIM + b * HDIM;   // h1T
        float acc = bfc[o];
        #pragma unroll
        for (int j = 0; j < HDIM; ++j)
            acc += fmaxf(hb[j], 0.f) * Wfc[o * HDIM + j];
        logits[b * 29 + o] = acc;
    }
}

extern "C" void kernel_launch(void* const* d_in, const int* in_sizes, int n_in,
                              void* d_out, int out_size, void* d_ws, size_t ws_size,
                              hipStream_t stream) {
    const float* x    = (const float*)d_in[0];
    const float* h    = (const float*)d_in[1];
    const float* Wih0 = (const float*)d_in[2];
    const float* Whh0 = (const float*)d_in[3];
    const float* bih0 = (const float*)d_in[4];
    const float* bhh0 = (const float*)d_in[5];
    const float* Wih1 = (const float*)d_in[6];
    const float* Whh1 = (const float*)d_in[7];
    const float* bih1 = (const float*)d_in[8];
    const float* bhh1 = (const float*)d_in[9];
    const float* Wfc  = (const float*)d_in[10];
    const float* bfc  = (const float*)d_in[11];

    float* out    = (float*)d_out;
    float* logits = out;                      // [256,29]
    float* hidden = out + BATCH * 29;         // [2,256,64]

    // Workspace: gx fp16 [B*T][192] = 196,608,000 B. All accesses in-bounds
    // (scan-side prefetch row clamped to T_STEPS-1).
    _Float16* gxp = (_Float16*)d_ws;

    gx_gemm<<<2048, 64, 0, stream>>>(x, Wih0, bih0, bhh0, gxp);
    gru_scan<<<BATCH, 192, 0, stream>>>(
        gxp, h, Whh0, bhh0, Wih1, Whh1, bih1, bhh1, hidden);
    fc_kernel<<<BATCH, 64, 0, stream>>>(hidden, Wfc, bfc, logits);
}